// Round 12
// baseline (832.026 us; speedup 1.0000x reference)
//
#include <hip/hip_runtime.h>
#include <hip/hip_fp16.h>
#include <math.h>

#define N_MEMBERS 2
#define N_NODES   65536
#define N_EDGES   1048576
#define N_LAYERS  12
#define D         64
#define OFF_STRIDE (N_NODES + 1)
#define NODE_MASK (N_NODES - 1)

// CSR build via dst-binned counting sort
#define NBINS       256          // bin = dst >> 8 (256 nodes per bin)
#define BIN_CAP     5120         // mean 4096, +16 sigma slack
#define EDGES_PER_WG 4096        // 256 threads x 16 edges

typedef _Float16 f16;
typedef f16   f16x8 __attribute__((ext_vector_type(8)));
typedef float f32x4 __attribute__((ext_vector_type(4)));

// ---------- preprocessing: binned CSR build ----------

__global__ __launch_bounds__(256) void bin_scatter_k(const int* __restrict__ ei,
                                                     int* __restrict__ binCursor,
                                                     unsigned int* __restrict__ binned) {
    int m = blockIdx.y;
    int t = threadIdx.x;
    int eBase = blockIdx.x * EDGES_PER_WG;
    __shared__ int hist[NBINS];
    __shared__ int base[NBINS];
    hist[t] = 0;
    __syncthreads();
    const int* srcp = ei + (size_t)(m * 2 + 0) * N_EDGES;
    const int* dstp = ei + (size_t)(m * 2 + 1) * N_EDGES;
    unsigned int pk[16];
    int bn[16], rk[16];
    #pragma unroll
    for (int i = 0; i < 16; i++) {
        int e = eBase + i * 256 + t;            // coalesced
        int src = srcp[e] & NODE_MASK;
        int dst = dstp[e] & NODE_MASK;
        int b = dst >> 8;
        bn[i] = b;
        pk[i] = ((unsigned)src << 8) | (unsigned)(dst & 255);
        rk[i] = atomicAdd(&hist[b], 1);         // local rank within WG's bin chunk
    }
    __syncthreads();
    base[t] = atomicAdd(&binCursor[m * NBINS + t], hist[t]);  // 256 global atomics/WG
    __syncthreads();
    unsigned int* bb = binned + (size_t)m * NBINS * BIN_CAP;
    #pragma unroll
    for (int i = 0; i < 16; i++) {
        int pos = base[bn[i]] + rk[i];
        if (pos < BIN_CAP)                       // overflow guard (16-sigma, never hit)
            bb[(size_t)bn[i] * BIN_CAP + pos] = pk[i];
    }
}

__global__ __launch_bounds__(256) void scan_bins_k(const int* __restrict__ cur,
                                                   int* __restrict__ bbase) {
    int m = blockIdx.x, t = threadIdx.x;
    __shared__ int sh[256];
    int v0 = cur[m * NBINS + t];
    sh[t] = v0;
    __syncthreads();
    for (int ofs = 1; ofs < 256; ofs <<= 1) {
        int v = sh[t];
        int a = (t >= ofs) ? sh[t - ofs] : 0;
        __syncthreads();
        sh[t] = v + a;
        __syncthreads();
    }
    bbase[m * NBINS + t] = sh[t] - v0;   // exclusive
}

__global__ __launch_bounds__(256) void bin_build_k(const unsigned int* __restrict__ binned,
                                                   const int* __restrict__ binCursor,
                                                   const int* __restrict__ bbase,
                                                   int* __restrict__ off,
                                                   float* __restrict__ dinv,
                                                   unsigned short* __restrict__ csr_src) {
    int m = blockIdx.y, b = blockIdx.x, t = threadIdx.x;
    int cnt   = binCursor[m * NBINS + b];
    int gbase = bbase[m * NBINS + b];
    const unsigned int* bb = binned + ((size_t)m * NBINS + b) * BIN_CAP;
    __shared__ int degl[256];
    __shared__ int offl[256];
    degl[t] = 0;
    __syncthreads();
    unsigned int ed[20];                          // rank<<24 | src<<8 | dstLow
    #pragma unroll
    for (int j = 0; j < 20; j++) {
        int i = t + j * 256;                      // coalesced
        ed[j] = 0;
        if (i < cnt) {
            unsigned int w = bb[i];
            int r = atomicAdd(&degl[w & 255], 1); // within-node rank (LDS)
            ed[j] = w | ((unsigned)r << 24);
        }
    }
    __syncthreads();
    int myDeg = degl[t];
    offl[t] = myDeg;
    __syncthreads();
    for (int ofs = 1; ofs < 256; ofs <<= 1) {     // inclusive scan
        int v = offl[t];
        int a = (t >= ofs) ? offl[t - ofs] : 0;
        __syncthreads();
        offl[t] = v + a;
        __syncthreads();
    }
    int myOff = gbase + offl[t] - myDeg;          // global exclusive offset
    int node = b * 256 + t;
    off[m * OFF_STRIDE + node] = myOff;
    if (b == NBINS - 1 && t == 255) off[m * OFF_STRIDE + N_NODES] = N_EDGES;
    dinv[m * N_NODES + node] = 1.0f / sqrtf((float)myDeg + 1.0f);
    offl[t] = myOff;
    __syncthreads();
    unsigned short* cs = csr_src + (size_t)m * N_EDGES;
    #pragma unroll
    for (int j = 0; j < 20; j++) {
        int i = t + j * 256;
        if (i < cnt) {
            int dl  = ed[j] & 255;
            int src = (ed[j] >> 8) & 0xFFFF;
            int r   = ed[j] >> 24;
            cs[offl[dl] + r] = (unsigned short)src;   // within ~8KB window
        }
    }
}

// ---------- presplit: W -> fragment-ordered split-fp16 table (once) --------
// Layout: Wsplit[ml][hl][t][s][lane][8 halves]; ml = m*N_LAYERS+layer.
__global__ __launch_bounds__(256) void presplit_k(const float* __restrict__ Wall,
                                                  __half* __restrict__ Wsplit) {
    int gid = blockIdx.x * 256 + threadIdx.x;     // 24*512 = 12288 threads
    int ml   = gid >> 9;
    int r    = gid & 511;
    int t    = (r >> 7) & 3;
    int s    = (r >> 6) & 1;
    int lane = r & 63;
    int c  = t * 16 + (lane & 15);
    int k0 = s * 32 + (lane >> 4) * 8;
    const float* Wg = Wall + (size_t)ml * D * D;
    __half* base = Wsplit + (size_t)ml * 8192;    // 2*4*2*64*8
    int fo = ((t * 2 + s) * 64 + lane) * 8;
    __half hi8[8], lo8[8];
    #pragma unroll
    for (int j = 0; j < 8; j++) {
        float v = Wg[(k0 + j) * D + c];
        f16 h = (f16)v;
        hi8[j] = *(__half*)&h;
        f16 l = (f16)(v - (float)h);
        lo8[j] = *(__half*)&l;
    }
    *(uint4*)(base + fo)        = *(uint4*)hi8;
    *(uint4*)(base + 4096 + fo) = *(uint4*)lo8;
}

// ---------- prescale: g = fp16(dinv * x) (layer-0 input table) ----------
__global__ __launch_bounds__(256) void prescale_k(const float* __restrict__ x,
                                                  const float* __restrict__ dinv,
                                                  __half* __restrict__ g) {
    int i = blockIdx.x * 256 + threadIdx.x;       // one per 8 floats
    float dv = dinv[i >> 3];                      // 64 floats per node
    float4 a = ((const float4*)x)[i * 2];
    float4 b = ((const float4*)x)[i * 2 + 1];
    union { __half2 h2[4]; uint4 u; } p;
    p.h2[0] = __floats2half2_rn(dv * a.x, dv * a.y);
    p.h2[1] = __floats2half2_rn(dv * a.z, dv * a.w);
    p.h2[2] = __floats2half2_rn(dv * b.x, dv * b.y);
    p.h2[3] = __floats2half2_rn(dv * b.z, dv * b.w);
    ((uint4*)g)[i] = p.u;
}

// ---------- per-layer aggregate (R7 exact): S = dinv .* (sum g[src] + g) ----
// 2 nodes per wave, interleaved gathers; plain (cached) loads/stores --
// nt was measured harmful (R10: FETCH unchanged, dur +10%).
__device__ __forceinline__ void cvt8(uint4 u, float* f) {
    const __half2* h2 = (const __half2*)&u;
    #pragma unroll
    for (int i = 0; i < 4; i++) {
        float2 t = __half22float2(h2[i]);
        f[2 * i]     = t.x;
        f[2 * i + 1] = t.y;
    }
}

__global__ __launch_bounds__(256) void aggregate_k(const __half* __restrict__ g,
                                                   __half* __restrict__ S,
                                                   const int* __restrict__ off,
                                                   const unsigned short* __restrict__ csr_src,
                                                   const float* __restrict__ dinv) {
    int bflat = blockIdx.x;
    int xcd   = bflat & 7;                 // round-robin XCD heuristic
    int m     = xcd >> 2;                  // member pinned to XCD half
    int slot  = ((bflat >> 3) << 2) | (xcd & 3);   // [0, N_NODES/8)
    int wav   = threadIdx.x >> 6;
    int nA    = slot * 8 + wav * 2;        // this wave's node pair
    int nB    = nA + 1;
    int lane = threadIdx.x & 63;
    int fg   = lane & 7;          // 16B chunk (8 halfs) of the 128B row
    int sub  = lane >> 3;         // 8 edges in flight per node
    const __half*         gm = g + (size_t)m * N_NODES * D;
    const int*            ob = off + m * OFF_STRIDE;
    const unsigned short* sb = csr_src + (size_t)m * N_EDGES;

    float accA[8], accB[8];
    #pragma unroll
    for (int i = 0; i < 8; i++) { accA[i] = 0.f; accB[i] = 0.f; }

    int eA0 = ob[nA], eA1 = ob[nA + 1], eB1 = ob[nB + 1];
    int eB0 = eA1;   // CSR contiguity: off[nB] == off[nA+1]
    #pragma unroll 2
    for (int eA = eA0, eB = eB0; (eA < eA1) || (eB < eB1); eA += 8, eB += 8) {
        int ia = eA + sub, ib = eB + sub;
        int idxA = (ia < eA1) ? ia : (eA1 - 1);
        int idxB = (ib < eB1) ? ib : (eB1 - 1);
        float wA = (ia < eA1) ? 1.0f : 0.0f;
        float wB = (ib < eB1) ? 1.0f : 0.0f;
        int sA = sb[idxA];
        int sB = sb[idxB];
        uint4 gA = *(const uint4*)(gm + (size_t)sA * D + fg * 8);
        uint4 gB = *(const uint4*)(gm + (size_t)sB * D + fg * 8);
        float fA[8], fB[8];
        cvt8(gA, fA);
        cvt8(gB, fB);
        #pragma unroll
        for (int i = 0; i < 8; i++) {
            accA[i] = fmaf(wA, fA[i], accA[i]);
            accB[i] = fmaf(wB, fB[i], accB[i]);
        }
    }
    #pragma unroll
    for (int msk = 8; msk < 64; msk <<= 1)
        #pragma unroll
        for (int i = 0; i < 8; i++) {
            accA[i] += __shfl_xor(accA[i], msk);
            accB[i] += __shfl_xor(accB[i], msk);
        }

    // self terms (butterfly left totals in ALL lanes; sub0 writes A, sub1 B)
    float dvA = dinv[m * N_NODES + nA];
    float dvB = dinv[m * N_NODES + nB];
    uint4 sgA = *(const uint4*)(gm + (size_t)nA * D + fg * 8);
    uint4 sgB = *(const uint4*)(gm + (size_t)nB * D + fg * 8);
    float sfA[8], sfB[8];
    cvt8(sgA, sfA);
    cvt8(sgB, sfB);
    __half* Sm = S + (size_t)m * N_NODES * D;
    if (sub == 0) {
        union { __half2 h2[4]; uint4 u; } p;
        #pragma unroll
        for (int i = 0; i < 4; i++)
            p.h2[i] = __floats2half2_rn(dvA * (accA[2 * i]     + sfA[2 * i]),
                                        dvA * (accA[2 * i + 1] + sfA[2 * i + 1]));
        *(uint4*)(Sm + (size_t)nA * D + fg * 8) = p.u;
    } else if (sub == 1) {
        union { __half2 h2[4]; uint4 u; } p;
        #pragma unroll
        for (int i = 0; i < 4; i++)
            p.h2[i] = __floats2half2_rn(dvB * (accB[2 * i]     + sfB[2 * i]),
                                        dvB * (accB[2 * i + 1] + sfB[2 * i + 1]));
        *(uint4*)(Sm + (size_t)nB * D + fg * 8) = p.u;
    }
}

// ---------- per-layer GEMM: split-t waves (2 col-tiles/wave) ---------------
// Transposed MFMA D = W^T S^T; fragment-ordered W (presplit_k). Each wave:
// 16 nodes x 2 t-tiles -> only 16 W-fragment loads (32 VGPR) and a short
// startup chain; 4096 blocks x 4 waves = 4x R11's wave count for latency
// hiding. Wave w: node-group = w>>1, t-pair = w&1.
// mid layers: g_next = fp16( dinv .* relu(S@W + b) )
// last layer: out    = fp32( S@W + b )
__global__ __launch_bounds__(256) void gemm_f16_k(const __half* __restrict__ S,
                                                  const __half* __restrict__ Wsplit,
                                                  const float* __restrict__ dinv,
                                                  const float* __restrict__ ball,
                                                  __half* __restrict__ gout,
                                                  float* __restrict__ fout,
                                                  int layer, int last) {
    int m = blockIdx.y;
    int lane = threadIdx.x & 63;
    int wav  = threadIdx.x >> 6;
    int nn   = lane & 15;
    int quad = lane >> 4;
    int ng   = wav >> 1;                  // node-group (16 nodes) within block
    int tp   = wav & 1;                   // t-pair: tiles {2tp, 2tp+1}

    const __half* Wf = Wsplit + (size_t)(m * N_LAYERS + layer) * 8192;
    f16x8 Bh[4], Bl[4];
    #pragma unroll
    for (int tt = 0; tt < 2; tt++)
        #pragma unroll
        for (int s = 0; s < 2; s++) {
            int t  = tp * 2 + tt;
            int fo = ((t * 2 + s) * 64 + lane) * 8;
            Bh[tt * 2 + s] = *(const f16x8*)(Wf + fo);
            Bl[tt * 2 + s] = *(const f16x8*)(Wf + 4096 + fo);
        }

    const __half* Sm = S + (size_t)m * N_NODES * D;
    const float*  bp = ball + (size_t)(m * N_LAYERS + layer) * D;
    __half*       gm = gout + (size_t)m * N_NODES * D;
    float*        fm = fout + (size_t)m * N_NODES * D;

    int node = blockIdx.x * 32 + ng * 16 + nn;
    const __half* srow = Sm + (size_t)node * D;
    f16x8 a0 = *(const f16x8*)(srow + quad * 8);        // k = quad*8..+7
    f16x8 a1 = *(const f16x8*)(srow + 32 + quad * 8);   // k = 32+quad*8..+7
    float dv = dinv[m * N_NODES + node];

    #pragma unroll
    for (int tt = 0; tt < 2; tt++) {
        int t = tp * 2 + tt;
        f32x4 c = {0.f, 0.f, 0.f, 0.f};
        c = __builtin_amdgcn_mfma_f32_16x16x32_f16(Bh[tt * 2 + 0], a0, c, 0, 0, 0);
        c = __builtin_amdgcn_mfma_f32_16x16x32_f16(Bh[tt * 2 + 1], a1, c, 0, 0, 0);
        c = __builtin_amdgcn_mfma_f32_16x16x32_f16(Bl[tt * 2 + 0], a0, c, 0, 0, 0);
        c = __builtin_amdgcn_mfma_f32_16x16x32_f16(Bl[tt * 2 + 1], a1, c, 0, 0, 0);
        float4 b4 = *(const float4*)(bp + t * 16 + quad * 4);
        float v0 = (float)c[0] + b4.x;
        float v1 = (float)c[1] + b4.y;
        float v2 = (float)c[2] + b4.z;
        float v3 = (float)c[3] + b4.w;
        int col = t * 16 + quad * 4;
        if (last) {
            *(float4*)(fm + (size_t)node * D + col) = make_float4(v0, v1, v2, v3);
        } else {
            union { __half2 h2[2]; uint2 u; } p;
            p.h2[0] = __floats2half2_rn(fmaxf(v0, 0.f) * dv, fmaxf(v1, 0.f) * dv);
            p.h2[1] = __floats2half2_rn(fmaxf(v2, 0.f) * dv, fmaxf(v3, 0.f) * dv);
            *(uint2*)(gm + (size_t)node * D + col) = p.u;
        }
    }
}

// ---------- host ----------

extern "C" void kernel_launch(void* const* d_in, const int* in_sizes, int n_in,
                              void* d_out, int out_size, void* d_ws, size_t ws_size,
                              hipStream_t stream) {
    (void)in_sizes; (void)n_in; (void)out_size; (void)ws_size;
    const float* x  = (const float*)d_in[0];
    const int*   ei = (const int*)d_in[1];
    const float* W  = (const float*)d_in[2];
    const float* b  = (const float*)d_in[3];
    float* out = (float*)d_out;

    char* ws = (char*)d_ws;
    size_t o = 0;
    auto take = [&](size_t bytes) -> void* {
        void* p = ws + o;
        o = (o + bytes + 255) & ~(size_t)255;
        return p;
    };
    float*          dinv      = (float*) take((size_t)N_MEMBERS * N_NODES * 4);
    int*            off       = (int*)   take((size_t)N_MEMBERS * OFF_STRIDE * 4);
    int*            binCursor = (int*)   take((size_t)N_MEMBERS * NBINS * 4);
    int*            bbase     = (int*)   take((size_t)N_MEMBERS * NBINS * 4);
    unsigned short* csr_src   = (unsigned short*)take((size_t)N_MEMBERS * N_EDGES * 2);
    __half*         Wsplit    = (__half*)take((size_t)N_MEMBERS * N_LAYERS * 8192 * 2);
    __half*         gbuf      = (__half*)take((size_t)N_MEMBERS * N_NODES * D * 2);
    __half*         Sbuf      = (__half*)take((size_t)N_MEMBERS * N_NODES * D * 2);
    // binned staging (10.5 MB) aliases Sbuf (16 MB): binned dies at bin_build_k;
    // Sbuf is first written by aggregate_k (layer 0), strictly after.
    unsigned int*   binned    = (unsigned int*)Sbuf;

    hipMemsetAsync(binCursor, 0, (size_t)N_MEMBERS * NBINS * 4, stream);

    presplit_k<<<dim3(N_MEMBERS * N_LAYERS * 512 / 256), 256, 0, stream>>>(W, Wsplit);
    bin_scatter_k<<<dim3(N_EDGES / EDGES_PER_WG, N_MEMBERS), 256, 0, stream>>>(
        ei, binCursor, binned);
    scan_bins_k<<<dim3(N_MEMBERS), 256, 0, stream>>>(binCursor, bbase);
    bin_build_k<<<dim3(NBINS, N_MEMBERS), 256, 0, stream>>>(
        binned, binCursor, bbase, off, dinv, csr_src);
    // g_0 = fp16(dinv .* x)  (needs dinv -> after bin_build_k)
    prescale_k<<<dim3((N_MEMBERS * N_NODES * D / 8) / 256), 256, 0, stream>>>(
        x, dinv, gbuf);

    for (int j = 0; j < N_LAYERS; j++) {
        // flattened grid: member decoded from (blockIdx.x & 7) >> 2 (XCD pinning)
        aggregate_k<<<dim3(N_MEMBERS * (N_NODES / 8)), 256, 0, stream>>>(
            gbuf, Sbuf, off, csr_src, dinv);
        gemm_f16_k<<<dim3(N_NODES / 32, N_MEMBERS), 256, 0, stream>>>(
            Sbuf, Wsplit, dinv, b, gbuf, out, j, (j == N_LAYERS - 1) ? 1 : 0);
    }
}

// Round 13
// 779.921 us; speedup vs baseline: 1.0668x; 1.0668x over previous
//
#include <hip/hip_runtime.h>
#include <hip/hip_fp16.h>
#include <math.h>

#define N_MEMBERS 2
#define N_NODES   65536
#define N_EDGES   1048576
#define N_LAYERS  12
#define D         64
#define OFF_STRIDE (N_NODES + 1)
#define NODE_MASK (N_NODES - 1)

// CSR build via dst-binned counting sort
#define NBINS       256          // bin = dst >> 8 (256 nodes per bin)
#define BIN_CAP     5120         // mean 4096, +16 sigma slack
#define EDGES_PER_WG 4096        // 256 threads x 16 edges

typedef _Float16 f16;
typedef f16   f16x8 __attribute__((ext_vector_type(8)));
typedef float f32x4 __attribute__((ext_vector_type(4)));

// ---------- preprocessing: binned CSR build ----------

__global__ __launch_bounds__(256) void bin_scatter_k(const int* __restrict__ ei,
                                                     int* __restrict__ binCursor,
                                                     unsigned int* __restrict__ binned) {
    int m = blockIdx.y;
    int t = threadIdx.x;
    int eBase = blockIdx.x * EDGES_PER_WG;
    __shared__ int hist[NBINS];
    __shared__ int base[NBINS];
    hist[t] = 0;
    __syncthreads();
    const int* srcp = ei + (size_t)(m * 2 + 0) * N_EDGES;
    const int* dstp = ei + (size_t)(m * 2 + 1) * N_EDGES;
    unsigned int pk[16];
    int bn[16], rk[16];
    #pragma unroll
    for (int i = 0; i < 16; i++) {
        int e = eBase + i * 256 + t;            // coalesced
        int src = srcp[e] & NODE_MASK;
        int dst = dstp[e] & NODE_MASK;
        int b = dst >> 8;
        bn[i] = b;
        pk[i] = ((unsigned)src << 8) | (unsigned)(dst & 255);
        rk[i] = atomicAdd(&hist[b], 1);         // local rank within WG's bin chunk
    }
    __syncthreads();
    base[t] = atomicAdd(&binCursor[m * NBINS + t], hist[t]);  // 256 global atomics/WG
    __syncthreads();
    unsigned int* bb = binned + (size_t)m * NBINS * BIN_CAP;
    #pragma unroll
    for (int i = 0; i < 16; i++) {
        int pos = base[bn[i]] + rk[i];
        if (pos < BIN_CAP)                       // overflow guard (16-sigma, never hit)
            bb[(size_t)bn[i] * BIN_CAP + pos] = pk[i];
    }
}

__global__ __launch_bounds__(256) void scan_bins_k(const int* __restrict__ cur,
                                                   int* __restrict__ bbase) {
    int m = blockIdx.x, t = threadIdx.x;
    __shared__ int sh[256];
    int v0 = cur[m * NBINS + t];
    sh[t] = v0;
    __syncthreads();
    for (int ofs = 1; ofs < 256; ofs <<= 1) {
        int v = sh[t];
        int a = (t >= ofs) ? sh[t - ofs] : 0;
        __syncthreads();
        sh[t] = v + a;
        __syncthreads();
    }
    bbase[m * NBINS + t] = sh[t] - v0;   // exclusive
}

__global__ __launch_bounds__(256) void bin_build_k(const unsigned int* __restrict__ binned,
                                                   const int* __restrict__ binCursor,
                                                   const int* __restrict__ bbase,
                                                   int* __restrict__ off,
                                                   float* __restrict__ dinv,
                                                   unsigned short* __restrict__ csr_src) {
    int m = blockIdx.y, b = blockIdx.x, t = threadIdx.x;
    int cnt   = binCursor[m * NBINS + b];
    int gbase = bbase[m * NBINS + b];
    const unsigned int* bb = binned + ((size_t)m * NBINS + b) * BIN_CAP;
    __shared__ int degl[256];
    __shared__ int offl[256];
    degl[t] = 0;
    __syncthreads();
    unsigned int ed[20];                          // rank<<24 | src<<8 | dstLow
    #pragma unroll
    for (int j = 0; j < 20; j++) {
        int i = t + j * 256;                      // coalesced
        ed[j] = 0;
        if (i < cnt) {
            unsigned int w = bb[i];
            int r = atomicAdd(&degl[w & 255], 1); // within-node rank (LDS)
            ed[j] = w | ((unsigned)r << 24);
        }
    }
    __syncthreads();
    int myDeg = degl[t];
    offl[t] = myDeg;
    __syncthreads();
    for (int ofs = 1; ofs < 256; ofs <<= 1) {     // inclusive scan
        int v = offl[t];
        int a = (t >= ofs) ? offl[t - ofs] : 0;
        __syncthreads();
        offl[t] = v + a;
        __syncthreads();
    }
    int myOff = gbase + offl[t] - myDeg;          // global exclusive offset
    int node = b * 256 + t;
    off[m * OFF_STRIDE + node] = myOff;
    if (b == NBINS - 1 && t == 255) off[m * OFF_STRIDE + N_NODES] = N_EDGES;
    dinv[m * N_NODES + node] = 1.0f / sqrtf((float)myDeg + 1.0f);
    offl[t] = myOff;
    __syncthreads();
    unsigned short* cs = csr_src + (size_t)m * N_EDGES;
    #pragma unroll
    for (int j = 0; j < 20; j++) {
        int i = t + j * 256;
        if (i < cnt) {
            int dl  = ed[j] & 255;
            int src = (ed[j] >> 8) & 0xFFFF;
            int r   = ed[j] >> 24;
            cs[offl[dl] + r] = (unsigned short)src;   // within ~8KB window
        }
    }
}

// ---------- presplit: W -> fragment-ordered split-fp16 table (once) --------
// Layout: Wsplit[ml][hl][t][s][lane][8 halves]; ml = m*N_LAYERS+layer.
__global__ __launch_bounds__(256) void presplit_k(const float* __restrict__ Wall,
                                                  __half* __restrict__ Wsplit) {
    int gid = blockIdx.x * 256 + threadIdx.x;     // 24*512 = 12288 threads
    int ml   = gid >> 9;
    int r    = gid & 511;
    int t    = (r >> 7) & 3;
    int s    = (r >> 6) & 1;
    int lane = r & 63;
    int c  = t * 16 + (lane & 15);
    int k0 = s * 32 + (lane >> 4) * 8;
    const float* Wg = Wall + (size_t)ml * D * D;
    __half* base = Wsplit + (size_t)ml * 8192;    // 2*4*2*64*8
    int fo = ((t * 2 + s) * 64 + lane) * 8;
    __half hi8[8], lo8[8];
    #pragma unroll
    for (int j = 0; j < 8; j++) {
        float v = Wg[(k0 + j) * D + c];
        f16 h = (f16)v;
        hi8[j] = *(__half*)&h;
        f16 l = (f16)(v - (float)h);
        lo8[j] = *(__half*)&l;
    }
    *(uint4*)(base + fo)        = *(uint4*)hi8;
    *(uint4*)(base + 4096 + fo) = *(uint4*)lo8;
}

// ---------- prescale: g = fp16(dinv * x) (layer-0 input table) ----------
__global__ __launch_bounds__(256) void prescale_k(const float* __restrict__ x,
                                                  const float* __restrict__ dinv,
                                                  __half* __restrict__ g) {
    int i = blockIdx.x * 256 + threadIdx.x;       // one per 8 floats
    float dv = dinv[i >> 3];                      // 64 floats per node
    float4 a = ((const float4*)x)[i * 2];
    float4 b = ((const float4*)x)[i * 2 + 1];
    union { __half2 h2[4]; uint4 u; } p;
    p.h2[0] = __floats2half2_rn(dv * a.x, dv * a.y);
    p.h2[1] = __floats2half2_rn(dv * a.z, dv * a.w);
    p.h2[2] = __floats2half2_rn(dv * b.x, dv * b.y);
    p.h2[3] = __floats2half2_rn(dv * b.z, dv * b.w);
    ((uint4*)g)[i] = p.u;
}

// ---------- per-layer aggregate (R7 exact): S = dinv .* (sum g[src] + g) ----
// 2 nodes per wave, interleaved gathers; plain (cached) loads/stores --
// nt was measured harmful (R10: FETCH unchanged, dur +10%).
__device__ __forceinline__ void cvt8(uint4 u, float* f) {
    const __half2* h2 = (const __half2*)&u;
    #pragma unroll
    for (int i = 0; i < 4; i++) {
        float2 t = __half22float2(h2[i]);
        f[2 * i]     = t.x;
        f[2 * i + 1] = t.y;
    }
}

__global__ __launch_bounds__(256) void aggregate_k(const __half* __restrict__ g,
                                                   __half* __restrict__ S,
                                                   const int* __restrict__ off,
                                                   const unsigned short* __restrict__ csr_src,
                                                   const float* __restrict__ dinv) {
    int bflat = blockIdx.x;
    int xcd   = bflat & 7;                 // round-robin XCD heuristic
    int m     = xcd >> 2;                  // member pinned to XCD half
    int slot  = ((bflat >> 3) << 2) | (xcd & 3);   // [0, N_NODES/8)
    int wav   = threadIdx.x >> 6;
    int nA    = slot * 8 + wav * 2;        // this wave's node pair
    int nB    = nA + 1;
    int lane = threadIdx.x & 63;
    int fg   = lane & 7;          // 16B chunk (8 halfs) of the 128B row
    int sub  = lane >> 3;         // 8 edges in flight per node
    const __half*         gm = g + (size_t)m * N_NODES * D;
    const int*            ob = off + m * OFF_STRIDE;
    const unsigned short* sb = csr_src + (size_t)m * N_EDGES;

    float accA[8], accB[8];
    #pragma unroll
    for (int i = 0; i < 8; i++) { accA[i] = 0.f; accB[i] = 0.f; }

    int eA0 = ob[nA], eA1 = ob[nA + 1], eB1 = ob[nB + 1];
    int eB0 = eA1;   // CSR contiguity: off[nB] == off[nA+1]
    #pragma unroll 2
    for (int eA = eA0, eB = eB0; (eA < eA1) || (eB < eB1); eA += 8, eB += 8) {
        int ia = eA + sub, ib = eB + sub;
        int idxA = (ia < eA1) ? ia : (eA1 - 1);
        int idxB = (ib < eB1) ? ib : (eB1 - 1);
        float wA = (ia < eA1) ? 1.0f : 0.0f;
        float wB = (ib < eB1) ? 1.0f : 0.0f;
        int sA = sb[idxA];
        int sB = sb[idxB];
        uint4 gA = *(const uint4*)(gm + (size_t)sA * D + fg * 8);
        uint4 gB = *(const uint4*)(gm + (size_t)sB * D + fg * 8);
        float fA[8], fB[8];
        cvt8(gA, fA);
        cvt8(gB, fB);
        #pragma unroll
        for (int i = 0; i < 8; i++) {
            accA[i] = fmaf(wA, fA[i], accA[i]);
            accB[i] = fmaf(wB, fB[i], accB[i]);
        }
    }
    #pragma unroll
    for (int msk = 8; msk < 64; msk <<= 1)
        #pragma unroll
        for (int i = 0; i < 8; i++) {
            accA[i] += __shfl_xor(accA[i], msk);
            accB[i] += __shfl_xor(accB[i], msk);
        }

    // self terms (butterfly left totals in ALL lanes; sub0 writes A, sub1 B)
    float dvA = dinv[m * N_NODES + nA];
    float dvB = dinv[m * N_NODES + nB];
    uint4 sgA = *(const uint4*)(gm + (size_t)nA * D + fg * 8);
    uint4 sgB = *(const uint4*)(gm + (size_t)nB * D + fg * 8);
    float sfA[8], sfB[8];
    cvt8(sgA, sfA);
    cvt8(sgB, sfB);
    __half* Sm = S + (size_t)m * N_NODES * D;
    if (sub == 0) {
        union { __half2 h2[4]; uint4 u; } p;
        #pragma unroll
        for (int i = 0; i < 4; i++)
            p.h2[i] = __floats2half2_rn(dvA * (accA[2 * i]     + sfA[2 * i]),
                                        dvA * (accA[2 * i + 1] + sfA[2 * i + 1]));
        *(uint4*)(Sm + (size_t)nA * D + fg * 8) = p.u;
    } else if (sub == 1) {
        union { __half2 h2[4]; uint4 u; } p;
        #pragma unroll
        for (int i = 0; i < 4; i++)
            p.h2[i] = __floats2half2_rn(dvB * (accB[2 * i]     + sfB[2 * i]),
                                        dvB * (accB[2 * i + 1] + sfB[2 * i + 1]));
        *(uint4*)(Sm + (size_t)nB * D + fg * 8) = p.u;
    }
}

// ---------- per-layer GEMM (R11 body + XCD-aligned grid) -------------------
// Transposed MFMA D = W^T S^T; fragment-ordered W (presplit_k); 2 node-groups
// per wave at N/128 blocks/member (measured best). NEW: flattened grid with
// the SAME member->XCD-half decode as aggregate_k, so S reads hit the L2 that
// aggregate just wrote, and g writes land where the next aggregate gathers.
// mid layers: g_next = fp16( dinv .* relu(S@W + b) )
// last layer: out    = fp32( S@W + b )
__global__ __launch_bounds__(256) void gemm_f16_k(const __half* __restrict__ S,
                                                  const __half* __restrict__ Wsplit,
                                                  const float* __restrict__ dinv,
                                                  const float* __restrict__ ball,
                                                  __half* __restrict__ gout,
                                                  float* __restrict__ fout,
                                                  int layer, int last) {
    int bflat = blockIdx.x;
    int xcd   = bflat & 7;                 // same decode as aggregate_k
    int m     = xcd >> 2;                  // member pinned to XCD half
    int slot  = ((bflat >> 3) << 2) | (xcd & 3);   // [0, N_NODES/128)
    int lane = threadIdx.x & 63;
    int wav  = threadIdx.x >> 6;
    int nn   = lane & 15;
    int quad = lane >> 4;

    const __half* Wf = Wsplit + (size_t)(m * N_LAYERS + layer) * 8192;
    f16x8 Bh[8], Bl[8];
    #pragma unroll
    for (int t = 0; t < 4; t++)
        #pragma unroll
        for (int s = 0; s < 2; s++) {
            int fo = ((t * 2 + s) * 64 + lane) * 8;
            Bh[t * 2 + s] = *(const f16x8*)(Wf + fo);
            Bl[t * 2 + s] = *(const f16x8*)(Wf + 4096 + fo);
        }

    const __half* Sm = S + (size_t)m * N_NODES * D;
    const float*  dm = dinv + m * N_NODES;
    const float*  bp = ball + (size_t)(m * N_LAYERS + layer) * D;
    __half*       gm = gout + (size_t)m * N_NODES * D;
    float*        fm = fout + (size_t)m * N_NODES * D;

    float4 b4[4];   // bias for cols t*16+quad*4 .. +3
    #pragma unroll
    for (int t = 0; t < 4; t++)
        b4[t] = *(const float4*)(bp + t * 16 + quad * 4);

    int base = slot * 128 + wav * 32;
    #pragma unroll
    for (int g = 0; g < 2; g++) {
        int node = base + g * 16 + nn;
        const __half* srow = Sm + (size_t)node * D;
        f16x8 a0 = *(const f16x8*)(srow + quad * 8);        // k = quad*8..+7
        f16x8 a1 = *(const f16x8*)(srow + 32 + quad * 8);   // k = 32+quad*8..+7
        float dv = dm[node];
        #pragma unroll
        for (int t = 0; t < 4; t++) {
            f32x4 c = {0.f, 0.f, 0.f, 0.f};
            c = __builtin_amdgcn_mfma_f32_16x16x32_f16(Bh[t * 2 + 0], a0, c, 0, 0, 0);
            c = __builtin_amdgcn_mfma_f32_16x16x32_f16(Bh[t * 2 + 1], a1, c, 0, 0, 0);
            c = __builtin_amdgcn_mfma_f32_16x16x32_f16(Bl[t * 2 + 0], a0, c, 0, 0, 0);
            c = __builtin_amdgcn_mfma_f32_16x16x32_f16(Bl[t * 2 + 1], a1, c, 0, 0, 0);
            float v0 = (float)c[0] + b4[t].x;
            float v1 = (float)c[1] + b4[t].y;
            float v2 = (float)c[2] + b4[t].z;
            float v3 = (float)c[3] + b4[t].w;
            int col = t * 16 + quad * 4;
            if (last) {
                *(float4*)(fm + (size_t)node * D + col) = make_float4(v0, v1, v2, v3);
            } else {
                union { __half2 h2[2]; uint2 u; } p;
                p.h2[0] = __floats2half2_rn(fmaxf(v0, 0.f) * dv, fmaxf(v1, 0.f) * dv);
                p.h2[1] = __floats2half2_rn(fmaxf(v2, 0.f) * dv, fmaxf(v3, 0.f) * dv);
                *(uint2*)(gm + (size_t)node * D + col) = p.u;
            }
        }
    }
}

// ---------- host ----------

extern "C" void kernel_launch(void* const* d_in, const int* in_sizes, int n_in,
                              void* d_out, int out_size, void* d_ws, size_t ws_size,
                              hipStream_t stream) {
    (void)in_sizes; (void)n_in; (void)out_size; (void)ws_size;
    const float* x  = (const float*)d_in[0];
    const int*   ei = (const int*)d_in[1];
    const float* W  = (const float*)d_in[2];
    const float* b  = (const float*)d_in[3];
    float* out = (float*)d_out;

    char* ws = (char*)d_ws;
    size_t o = 0;
    auto take = [&](size_t bytes) -> void* {
        void* p = ws + o;
        o = (o + bytes + 255) & ~(size_t)255;
        return p;
    };
    float*          dinv      = (float*) take((size_t)N_MEMBERS * N_NODES * 4);
    int*            off       = (int*)   take((size_t)N_MEMBERS * OFF_STRIDE * 4);
    int*            binCursor = (int*)   take((size_t)N_MEMBERS * NBINS * 4);
    int*            bbase     = (int*)   take((size_t)N_MEMBERS * NBINS * 4);
    unsigned short* csr_src   = (unsigned short*)take((size_t)N_MEMBERS * N_EDGES * 2);
    __half*         Wsplit    = (__half*)take((size_t)N_MEMBERS * N_LAYERS * 8192 * 2);
    __half*         gbuf      = (__half*)take((size_t)N_MEMBERS * N_NODES * D * 2);
    __half*         Sbuf      = (__half*)take((size_t)N_MEMBERS * N_NODES * D * 2);
    // binned staging (10.5 MB) aliases Sbuf (16 MB): binned dies at bin_build_k;
    // Sbuf is first written by aggregate_k (layer 0), strictly after.
    unsigned int*   binned    = (unsigned int*)Sbuf;

    hipMemsetAsync(binCursor, 0, (size_t)N_MEMBERS * NBINS * 4, stream);

    presplit_k<<<dim3(N_MEMBERS * N_LAYERS * 512 / 256), 256, 0, stream>>>(W, Wsplit);
    bin_scatter_k<<<dim3(N_EDGES / EDGES_PER_WG, N_MEMBERS), 256, 0, stream>>>(
        ei, binCursor, binned);
    scan_bins_k<<<dim3(N_MEMBERS), 256, 0, stream>>>(binCursor, bbase);
    bin_build_k<<<dim3(NBINS, N_MEMBERS), 256, 0, stream>>>(
        binned, binCursor, bbase, off, dinv, csr_src);
    // g_0 = fp16(dinv .* x)  (needs dinv -> after bin_build_k)
    prescale_k<<<dim3((N_MEMBERS * N_NODES * D / 8) / 256), 256, 0, stream>>>(
        x, dinv, gbuf);

    for (int j = 0; j < N_LAYERS; j++) {
        // both kernels use the flattened grid with member = (blockIdx.x&7)>>2
        aggregate_k<<<dim3(N_MEMBERS * (N_NODES / 8)), 256, 0, stream>>>(
            gbuf, Sbuf, off, csr_src, dinv);
        gemm_f16_k<<<dim3(N_MEMBERS * (N_NODES / 128)), 256, 0, stream>>>(
            Sbuf, Wsplit, dinv, b, gbuf, out, j, (j == N_LAYERS - 1) ? 1 : 0);
    }
}